// Round 15
// baseline (501.266 us; speedup 1.0000x reference)
//
#include <hip/hip_runtime.h>
#include <math.h>

#define DDIM 256
#define NSPLIT 4
#define TILES_PER_SPLIT 16   // 16 tiles x 32 codes = 512 codes per split
#define TILE_CODES 32
#define TILE_BYTES 16384     // 32 codes x 256 dims x 2B (panel layout)
#define ROWS_PER_BLOCK 128   // 8 waves x 16 rows

typedef __attribute__((ext_vector_type(8))) short short8v;
typedef __attribute__((ext_vector_type(4))) float float4v;
typedef unsigned int u32;
typedef unsigned short u16;

// ---- RNE float -> bf16 ----
__device__ __forceinline__ short f2bf(float x) {
    u32 u = __float_as_uint(x);
    u = u + 0x7fffu + ((u >> 16) & 1u);
    return (short)(u >> 16);
}

// ---- numpy pairwise-sum simulation (bit-faithful for n=256 contiguous) ----
__device__ __forceinline__ float np_sq_chain(const float* v, int lane) {
    #pragma clang fp contract(off)
    const int half = lane >> 3, j = lane & 7;
    const float* base = v + half * 128 + j;
    float x = base[0];
    float c = x * x;
    #pragma unroll
    for (int m = 1; m < 16; ++m) {
        float y = base[8 * m];
        float s = y * y;
        c = c + s;
    }
    return c;
}

__device__ __forceinline__ float np_combine16(const float* c) {
    #pragma clang fp contract(off)
    float L = ((c[0] + c[1]) + (c[2] + c[3])) + ((c[4] + c[5]) + (c[6] + c[7]));
    float R = ((c[8] + c[9]) + (c[10] + c[11])) + ((c[12] + c[13]) + (c[14] + c[15]));
    return L + R;
}

// ---- top-3 insertion (strict <, preserves first-insertion on ties) ----
__device__ __forceinline__ void ins3(float m, int k,
                                     float& v0, float& v1, float& v2,
                                     int& i0, int& i1, int& i2) {
    if (m < v0)      { v2 = v1; i2 = i1; v1 = v0; i1 = i0; v0 = m; i0 = k; }
    else if (m < v1) { v2 = v1; i2 = i1; v1 = m;  i1 = k; }
    else if (m < v2) { v2 = m;  i2 = k; }
}

// ---------------- kernel 2: numpy-faithful code norms ||e_k||^2 (+ zero counts) ----------------
__global__ void code_norms_np_kernel(const float* __restrict__ e, float* __restrict__ e2,
                                     int* __restrict__ counts) {
    __shared__ float buf[DDIM];
    __shared__ float ch[16];
    int k = blockIdx.x;
    int t = threadIdx.x;  // 64 threads = 1 wave
    if (t == 0) counts[k] = 0;   // fused zero_counts (grid == K)
    float4 v = *(const float4*)&e[(size_t)k * DDIM + t * 4];
    *(float4*)&buf[t * 4] = v;
    __syncthreads();
    if (t < 16) ch[t] = np_sq_chain(buf, t);
    __syncthreads();
    if (t == 0) e2[k] = np_combine16(ch);
}

// ---------------- kernel 2b: convert e -> bf16 panel layout ----------------
// ebf_p[tile=k/32][d8=0..31][r=k%32][8 shorts]; tile = 16KB contiguous.
__global__ void convert_permute_e_kernel(const float* __restrict__ e, char* __restrict__ ebf_p) {
    int id = blockIdx.x * 256 + threadIdx.x;   // id = k*32 + d8, total K*32
    int k = id >> 5, d8 = id & 31;
    const float* s = &e[(size_t)k * DDIM + d8 * 8];
    float4 f0 = *(const float4*)s;
    float4 f1 = *(const float4*)(s + 4);
    short8v v;
    v[0] = f2bf(f0.x); v[1] = f2bf(f0.y); v[2] = f2bf(f0.z); v[3] = f2bf(f0.w);
    v[4] = f2bf(f1.x); v[5] = f2bf(f1.y); v[6] = f2bf(f1.z); v[7] = f2bf(f1.w);
    *(short8v*)(ebf_p + ((size_t)(k >> 5) << 14) + d8 * 512 + (k & 31) * 16) = v;
}

// ---------------- kernel 3: R9 streaming structure at 32 WAVES/CU ----------------
// OCCUPANCY-CONFOUND FIX (round 15). The "walled at 264us" claim was derived
// from confounded points: R8/R9's grid (512 blocks x 8 waves = 4096 waves)
// CAPS occupancy at 50% (measured 40%); the only high-occupancy round (R3,
// 73%) was simultaneously spilling through a 64-reg budget. Arithmetic says
// the wall is latency-bound, not throughput-bound: 8192 load-instrs/CU over
// 634kcy = 1 load per 77cy/CU, 5-20x below any TA/L1/L2 instruction-rate
// limit, with ~86% of cycles in vmcnt waits. In that regime time scales
// inversely with resident waves -- and the best structure was never run
// above 16 waves/CU. This round: NSPLIT=4 -> grid (256,4) = 1024 blocks x
// 8 waves = 8192 waves = 32/CU = 100% capacity (VGPR 40 -> 8 waves/SIMD;
// LDS 2KB; exactly 4 blocks/CU). Per-wave code identical to R9; candidate
// semantics = R0/R5's verified 4-split top-3 + 12-pool refine.
// Falsifiable: Occupancy >= 70%. If occupancy rises but dur >= 240us, the
// wall is structural at ALL occupancies -> declare roofline next round.
__global__ __launch_bounds__(512, 1)
void vq_cand_kernel(const float* __restrict__ z, const char* __restrict__ ebf_p,
                    const float* __restrict__ e2, float* __restrict__ cand_v,
                    u16* __restrict__ cand_i, int N) {
    __shared__ float e2s[512];
    const int t    = threadIdx.x;
    const int w    = t >> 6;        // wave 0..7
    const int lane = t & 63;
    const int quad = lane >> 4;
    const int l15  = lane & 15;
    const int s    = blockIdx.y;
    const int rw   = blockIdx.x * ROWS_PER_BLOCK + w * 16;   // this wave's 16 rows

    // e2 for this split -> LDS once (512 threads x 1 float)
    e2s[t] = e2[s * 512 + t];

    // ---- persistent z fragments: 16 rows x 256 dims per wave, NAMED scalars ----
    short8v zf0, zf1, zf2, zf3, zf4, zf5, zf6, zf7;
    {
        const float* zr = &z[(size_t)(rw + l15) * DDIM];
#define LOADZ(I, DST)                                                        \
        {                                                                    \
            int d0 = (I) * 32 + quad * 8;                                    \
            float4 f0 = *(const float4*)&zr[d0];                             \
            float4 f1 = *(const float4*)&zr[d0 + 4];                         \
            short8v v;                                                       \
            v[0] = f2bf(f0.x); v[1] = f2bf(f0.y);                            \
            v[2] = f2bf(f0.z); v[3] = f2bf(f0.w);                            \
            v[4] = f2bf(f1.x); v[5] = f2bf(f1.y);                            \
            v[6] = f2bf(f1.z); v[7] = f2bf(f1.w);                            \
            DST = v;                                                         \
        }
        LOADZ(0, zf0) LOADZ(1, zf1) LOADZ(2, zf2) LOADZ(3, zf3)
        LOADZ(4, zf4) LOADZ(5, zf5) LOADZ(6, zf6) LOADZ(7, zf7)
#undef LOADZ
    }

    __syncthreads();   // e2s ready; the ONLY barrier in this kernel

    float v0 = 3.4e38f, v1 = 3.4e38f, v2 = 3.4e38f;
    int   i0 = 0x7fff,  i1 = 0x7fff,  i2 = 0x7fff;

    const char* sbase = ebf_p + (size_t)s * TILES_PER_SPLIT * TILE_BYTES
                      + quad * 512 + l15 * 16;

    // ---- 16 tiles streamed from global/L2, zero synchronization ----
    #pragma unroll 1
    for (int tt = 0; tt < TILES_PER_SPLIT; ++tt) {
        const char* tg = sbase + (size_t)tt * TILE_BYTES;

        float4v acc0 = (float4v)0.0f, acc1 = (float4v)0.0f;

#define STEP(KK, ZF)                                                         \
        {                                                                    \
            short8v a0 = *(const short8v*)(tg + (KK) * 2048);                \
            short8v a1 = *(const short8v*)(tg + (KK) * 2048 + 256);          \
            acc0 = __builtin_amdgcn_mfma_f32_16x16x32_bf16(a0, ZF, acc0, 0, 0, 0); \
            acc1 = __builtin_amdgcn_mfma_f32_16x16x32_bf16(a1, ZF, acc1, 0, 0, 0); \
        }
        STEP(0, zf0) STEP(1, zf1) STEP(2, zf2) STEP(3, zf3)
        STEP(4, zf4) STEP(5, zf5) STEP(6, zf6) STEP(7, zf7)
#undef STEP

        // epilogue: fold tile scores m(k)=e2[k]-2S into per-row top-3
        // (R0/R5's exact per-row visit order -> identical tie behavior)
        const int kloc  = tt * TILE_CODES;
        const int kbase = s * 512 + kloc;
        float4 e2a = *(const float4*)&e2s[kloc + quad * 4];
        float4 e2b = *(const float4*)&e2s[kloc + 16 + quad * 4];
        float m;
        m = fmaf(-2.0f, acc0[0], e2a.x); ins3(m, kbase + quad * 4 + 0,      v0, v1, v2, i0, i1, i2);
        m = fmaf(-2.0f, acc1[0], e2b.x); ins3(m, kbase + 16 + quad * 4 + 0, v0, v1, v2, i0, i1, i2);
        m = fmaf(-2.0f, acc0[1], e2a.y); ins3(m, kbase + quad * 4 + 1,      v0, v1, v2, i0, i1, i2);
        m = fmaf(-2.0f, acc1[1], e2b.y); ins3(m, kbase + 16 + quad * 4 + 1, v0, v1, v2, i0, i1, i2);
        m = fmaf(-2.0f, acc0[2], e2a.z); ins3(m, kbase + quad * 4 + 2,      v0, v1, v2, i0, i1, i2);
        m = fmaf(-2.0f, acc1[2], e2b.z); ins3(m, kbase + 16 + quad * 4 + 2, v0, v1, v2, i0, i1, i2);
        m = fmaf(-2.0f, acc0[3], e2a.w); ins3(m, kbase + quad * 4 + 3,      v0, v1, v2, i0, i1, i2);
        m = fmaf(-2.0f, acc1[3], e2b.w); ins3(m, kbase + 16 + quad * 4 + 3, v0, v1, v2, i0, i1, i2);
    }

    // ---- cross-quad merge via shuffles: 4 quads x top-3 -> split top-3 ----
    {
        float bm0 = 3.4e38f, bm1 = 3.4e38f, bm2 = 3.4e38f;
        int   bk0 = 0x7fff,  bk1 = 0x7fff,  bk2 = 0x7fff;
        #pragma unroll
        for (int q = 0; q < 4; ++q) {
            int src = l15 + q * 16;
            float m0 = __shfl(v0, src); int k0 = __shfl(i0, src);
            float m1 = __shfl(v1, src); int k1 = __shfl(i1, src);
            float m2 = __shfl(v2, src); int k2 = __shfl(i2, src);
            ins3(m0, k0, bm0, bm1, bm2, bk0, bk1, bk2);
            ins3(m1, k1, bm0, bm1, bm2, bk0, bk1, bk2);
            ins3(m2, k2, bm0, bm1, bm2, bk0, bk1, bk2);
        }
        // split-major layout cand[s][n][3]: contiguous per-block writes
        if (quad == 0) {
            size_t base = ((size_t)s * N + (rw + l15)) * 3;
            cand_v[base]     = bm0;  cand_i[base]     = (u16)bk0;
            cand_v[base + 1] = bm1;  cand_i[base + 1] = (u16)bk1;
            cand_v[base + 2] = bm2;  cand_i[base + 2] = (u16)bk2;
        }
    }
}

// ---------------- kernel 4: 12-pool prefilter + ILP re-rank (verified pieces) ----------------
// Prefilter 12 -> top-6 by bf16 score (R0/R5's verified loop and read order),
// then R14's verified ILP tail: six gathers into named regs, six fp64 dots,
// interleaved shuffle-reduction trees, register winner-select. Values, orders,
// and tie-breaks bit-identical to the R5 path.
__global__ void refine_fused_kernel(const float* __restrict__ z, const float* __restrict__ e,
                                    const float* __restrict__ e2np,
                                    const float* __restrict__ cand_v,
                                    const u16* __restrict__ cand_i,
                                    int* __restrict__ counts, float* __restrict__ partials,
                                    float* __restrict__ out_zq, float* __restrict__ out_idx,
                                    int N) {
    __shared__ float buf[4][DDIM];
    __shared__ float ch[4][16];
    __shared__ float wsum[4];
    const int w = threadIdx.x >> 6;
    const int t = threadIdx.x & 63;
    const int n = blockIdx.x * 4 + w;

    float4 zv = *(const float4*)&z[(size_t)n * DDIM + t * 4];
    *(float4*)&buf[w][t * 4] = zv;
    __syncthreads();
    if (t < 16) ch[w][t] = np_sq_chain(buf[w], t);
    __syncthreads();

    // ---- prefilter: 12 -> top-6 by bf16 score (uniform across wave) ----
    float bv[6]; int bi[6];
    #pragma unroll
    for (int c = 0; c < 6; ++c) { bv[c] = 3.4e38f; bi[c] = 0x7fffffff; }
    #pragma unroll
    for (int c = 0; c < 12; ++c) {
        int sp = c / 3, j = c - sp * 3;
        size_t off = ((size_t)sp * N + n) * 3 + j;
        float v  = cand_v[off];
        int   id = (int)cand_i[off];
        #pragma unroll
        for (int x = 0; x < 6; ++x) {
            if (v < bv[x] || (v == bv[x] && id < bi[x])) {
                for (int d = 5; d > x; --d) { bv[d] = bv[d - 1]; bi[d] = bi[d - 1]; }
                bv[x] = v; bi[x] = id;
                break;
            }
        }
    }

    // ---- all six gathers issued back-to-back into named registers ----
    float4 ev0 = *(const float4*)&e[(size_t)bi[0] * DDIM + t * 4];
    float4 ev1 = *(const float4*)&e[(size_t)bi[1] * DDIM + t * 4];
    float4 ev2 = *(const float4*)&e[(size_t)bi[2] * DDIM + t * 4];
    float4 ev3 = *(const float4*)&e[(size_t)bi[3] * DDIM + t * 4];
    float4 ev4 = *(const float4*)&e[(size_t)bi[4] * DDIM + t * 4];
    float4 ev5 = *(const float4*)&e[(size_t)bi[5] * DDIM + t * 4];

    // ---- six fp64 partial dots (same expression as verified rounds) ----
    double p0 = (double)zv.x * (double)ev0.x + (double)zv.y * (double)ev0.y
              + (double)zv.z * (double)ev0.z + (double)zv.w * (double)ev0.w;
    double p1 = (double)zv.x * (double)ev1.x + (double)zv.y * (double)ev1.y
              + (double)zv.z * (double)ev1.z + (double)zv.w * (double)ev1.w;
    double p2 = (double)zv.x * (double)ev2.x + (double)zv.y * (double)ev2.y
              + (double)zv.z * (double)ev2.z + (double)zv.w * (double)ev2.w;
    double p3 = (double)zv.x * (double)ev3.x + (double)zv.y * (double)ev3.y
              + (double)zv.z * (double)ev3.z + (double)zv.w * (double)ev3.w;
    double p4 = (double)zv.x * (double)ev4.x + (double)zv.y * (double)ev4.y
              + (double)zv.z * (double)ev4.z + (double)zv.w * (double)ev4.w;
    double p5 = (double)zv.x * (double)ev5.x + (double)zv.y * (double)ev5.y
              + (double)zv.z * (double)ev5.z + (double)zv.w * (double)ev5.w;

    // ---- six reduction trees, interleaved level-by-level ----
    #pragma unroll
    for (int o = 32; o > 0; o >>= 1) {
        p0 += __shfl_down(p0, o);
        p1 += __shfl_down(p1, o);
        p2 += __shfl_down(p2, o);
        p3 += __shfl_down(p3, o);
        p4 += __shfl_down(p4, o);
        p5 += __shfl_down(p5, o);
    }
    float d0 = (float)p0, d1 = (float)p1, d2 = (float)p2;
    float d3 = (float)p3, d4 = (float)p4, d5 = (float)p5;

    int bk = 0;
    if (t == 0) {
        #pragma clang fp contract(off)
        float sx = np_combine16(ch[w]);
        float bd = 3.4e38f;
        bk = 0x7fffffff;
#define SEL(DC, BIC)                                                         \
        {                                                                    \
            float twod = 2.0f * (DC);                                        \
            float t1 = sx - twod;                                            \
            float d2v = t1 + e2np[BIC];                                      \
            d2v = fmaxf(d2v, 0.0f);                                          \
            float d = sqrtf(d2v);                                            \
            if (d < bd || (d == bd && (BIC) < bk)) { bd = d; bk = (BIC); }   \
        }
        SEL(d0, bi[0]) SEL(d1, bi[1]) SEL(d2, bi[2])
        SEL(d3, bi[3]) SEL(d4, bi[4]) SEL(d5, bi[5])
#undef SEL
    }
    int wk = __shfl(bk, 0);

    // ---- winner row already in registers: uniform select, no re-gather ----
    float4 ev;
    if      (wk == bi[0]) ev = ev0;
    else if (wk == bi[1]) ev = ev1;
    else if (wk == bi[2]) ev = ev2;
    else if (wk == bi[3]) ev = ev3;
    else if (wk == bi[4]) ev = ev4;
    else                  ev = ev5;

    *(float4*)&out_zq[(size_t)n * DDIM + t * 4] = ev;
    float dx = zv.x - ev.x, dy = zv.y - ev.y, dz = zv.z - ev.z, dw = zv.w - ev.w;
    float sq = dx * dx + dy * dy + dz * dz + dw * dw;
    #pragma unroll
    for (int o = 32; o > 0; o >>= 1) sq += __shfl_down(sq, o);
    if (t == 0) {
        wsum[w] = sq;
        atomicAdd(&counts[wk], 1);
        out_idx[n] = (float)wk;
    }
    __syncthreads();
    if (threadIdx.x == 0)
        partials[blockIdx.x] = wsum[0] + wsum[1] + wsum[2] + wsum[3];
}

// ---------------- kernel 5: finalize loss ----------------
__global__ void finalize_kernel(const int* __restrict__ counts, const float* __restrict__ partials,
                                float* __restrict__ out_loss, int K, int NB,
                                float invN, float invND) {
    int t = threadIdx.x;
    double ent = 0.0, sq = 0.0;
    for (int k = t; k < K; k += 256) {
        float p = (float)counts[k] * invN;
        ent += (double)(p * logf(p + 1e-10f));
    }
    for (int i = t; i < NB; i += 256) sq += (double)partials[i];
    #pragma unroll
    for (int o = 32; o > 0; o >>= 1) {
        ent += __shfl_down(ent, o);
        sq  += __shfl_down(sq, o);
    }
    __shared__ double e4[4], s4[4];
    if ((t & 63) == 0) { e4[t >> 6] = ent; s4[t >> 6] = sq; }
    __syncthreads();
    if (t == 0) {
        double esum = e4[0] + e4[1] + e4[2] + e4[3];
        double ssum = s4[0] + s4[1] + s4[2] + s4[3];
        float perp = expf((float)(-esum));
        float mean = (float)ssum * invND;
        out_loss[0] = 1.25f * mean - 0.01f * perp;
    }
}

extern "C" void kernel_launch(void* const* d_in, const int* in_sizes, int n_in,
                              void* d_out, int out_size, void* d_ws, size_t ws_size,
                              hipStream_t stream) {
    const float* z = (const float*)d_in[0];
    const float* e = (const float*)d_in[1];
    const int N = in_sizes[0] / DDIM;   // 32768
    const int K = in_sizes[1] / DDIM;   // 2048

    float* out      = (float*)d_out;
    float* out_zq   = out;
    float* out_loss = out + (size_t)N * DDIM;
    float* out_idx  = out_loss + 1;

    // ws layout (bytes):
    //   counts[K]            @ 0        (8 KB)
    //   e2np[K]              @ 8192     (8 KB)
    //   partials[N/4]        @ 16384    (32 KB)
    //   cand_v[4][N][3] f32  @ 49152    (1.5 MB)
    //   cand_i[4][N][3] u16  @ 1622016  (768 KB)
    //   ebf_p (1 MB panels)  @ 2408448  -> total ~3.46 MB
    int*   counts   = (int*)d_ws;
    float* e2np     = (float*)((char*)d_ws + 8192);
    float* partials = (float*)((char*)d_ws + 16384);
    float* cand_v   = (float*)((char*)d_ws + 49152);
    u16*   cand_i   = (u16*)((char*)d_ws + 1622016);
    char*  ebf_p    = (char*)d_ws + 2408448;

    code_norms_np_kernel<<<K, 64, 0, stream>>>(e, e2np, counts);
    convert_permute_e_kernel<<<K * 32 / 256, 256, 0, stream>>>(e, ebf_p);
    vq_cand_kernel<<<dim3(N / ROWS_PER_BLOCK, NSPLIT), 512, 0, stream>>>(z, ebf_p, e2np,
                                                                         cand_v, cand_i, N);
    refine_fused_kernel<<<N / 4, 256, 0, stream>>>(z, e, e2np, cand_v, cand_i,
                                                   counts, partials, out_zq, out_idx, N);
    finalize_kernel<<<1, 256, 0, stream>>>(counts, partials, out_loss, K, N / 4,
                                           1.0f / (float)N, 1.0f / (float)(N * DDIM));
}

// Round 16
// 402.446 us; speedup vs baseline: 1.2455x; 1.2455x over previous
//
#include <hip/hip_runtime.h>
#include <math.h>

#define DDIM 256
#define NSPLIT 2
#define TILES_PER_SPLIT 32   // 32 tiles x 32 codes = 1024 codes per split
#define TILE_CODES 32
#define TILE_BYTES 16384     // 32 codes x 256 dims x 2B (panel layout)
#define ROWS_PER_BLOCK 128   // 8 waves x 16 rows

typedef __attribute__((ext_vector_type(8))) short short8v;
typedef __attribute__((ext_vector_type(4))) float float4v;
typedef unsigned int u32;
typedef unsigned short u16;

// ---- RNE float -> bf16 ----
__device__ __forceinline__ short f2bf(float x) {
    u32 u = __float_as_uint(x);
    u = u + 0x7fffu + ((u >> 16) & 1u);
    return (short)(u >> 16);
}

// ---- numpy pairwise-sum simulation (bit-faithful for n=256 contiguous) ----
__device__ __forceinline__ float np_sq_chain(const float* v, int lane) {
    #pragma clang fp contract(off)
    const int half = lane >> 3, j = lane & 7;
    const float* base = v + half * 128 + j;
    float x = base[0];
    float c = x * x;
    #pragma unroll
    for (int m = 1; m < 16; ++m) {
        float y = base[8 * m];
        float s = y * y;
        c = c + s;
    }
    return c;
}

__device__ __forceinline__ float np_combine16(const float* c) {
    #pragma clang fp contract(off)
    float L = ((c[0] + c[1]) + (c[2] + c[3])) + ((c[4] + c[5]) + (c[6] + c[7]));
    float R = ((c[8] + c[9]) + (c[10] + c[11])) + ((c[12] + c[13]) + (c[14] + c[15]));
    return L + R;
}

// ---- top-3 insertion (strict <, preserves first-insertion on ties) ----
__device__ __forceinline__ void ins3(float m, int k,
                                     float& v0, float& v1, float& v2,
                                     int& i0, int& i1, int& i2) {
    if (m < v0)      { v2 = v1; i2 = i1; v1 = v0; i1 = i0; v0 = m; i0 = k; }
    else if (m < v1) { v2 = v1; i2 = i1; v1 = m;  i1 = k; }
    else if (m < v2) { v2 = m;  i2 = k; }
}

// ---------------- kernel 2: numpy-faithful code norms ||e_k||^2 (+ zero counts) ----------------
__global__ void code_norms_np_kernel(const float* __restrict__ e, float* __restrict__ e2,
                                     int* __restrict__ counts) {
    __shared__ float buf[DDIM];
    __shared__ float ch[16];
    int k = blockIdx.x;
    int t = threadIdx.x;  // 64 threads = 1 wave
    if (t == 0) counts[k] = 0;   // fused zero_counts (grid == K)
    float4 v = *(const float4*)&e[(size_t)k * DDIM + t * 4];
    *(float4*)&buf[t * 4] = v;
    __syncthreads();
    if (t < 16) ch[t] = np_sq_chain(buf, t);
    __syncthreads();
    if (t == 0) e2[k] = np_combine16(ch);
}

// ---------------- kernel 2b: convert e -> bf16 panel layout ----------------
// ebf_p[tile=k/32][d8=0..31][r=k%32][8 shorts]; tile = 16KB contiguous.
__global__ void convert_permute_e_kernel(const float* __restrict__ e, char* __restrict__ ebf_p) {
    int id = blockIdx.x * 256 + threadIdx.x;   // id = k*32 + d8, total K*32
    int k = id >> 5, d8 = id & 31;
    const float* s = &e[(size_t)k * DDIM + d8 * 8];
    float4 f0 = *(const float4*)s;
    float4 f1 = *(const float4*)(s + 4);
    short8v v;
    v[0] = f2bf(f0.x); v[1] = f2bf(f0.y); v[2] = f2bf(f0.z); v[3] = f2bf(f0.w);
    v[4] = f2bf(f1.x); v[5] = f2bf(f1.y); v[6] = f2bf(f1.z); v[7] = f2bf(f1.w);
    *(short8v*)(ebf_p + ((size_t)(k >> 5) << 14) + d8 * 512 + (k & 31) * 16) = v;
}

// ---------------- kernel 3: barrier-free streaming MFMA (R9, session-best) ----------------
// FINAL CONFIGURATION. 16 rounds bracketed: sync style (lockstep/counted-
// vmcnt/none), spill (eliminated), operand traffic (8x swing), prefetch depth
// (reg lookahead, LDS dbuf), reuse factor (16/32/128 rows/wave), occupancy
// (11->73%: R15 at 56% was WORSE -- shared per-CU/L2 operand-service rate,
// not per-wave latency), refine restructuring, setup fusion -- every
// deviation neutral or negative. This is the measured optimum: 16 waves/CU,
// named-scalar fragments (no ext_vector arrays -> no scratch), codes
// streamed from L2, zero loop synchronization.
__global__ __launch_bounds__(512, 1)
void vq_cand_kernel(const float* __restrict__ z, const char* __restrict__ ebf_p,
                    const float* __restrict__ e2, float* __restrict__ cand_v,
                    u16* __restrict__ cand_i, int N) {
    __shared__ float e2s[1024];
    const int t    = threadIdx.x;
    const int w    = t >> 6;        // wave 0..7
    const int lane = t & 63;
    const int quad = lane >> 4;
    const int l15  = lane & 15;
    const int s    = blockIdx.y;
    const int rw   = blockIdx.x * ROWS_PER_BLOCK + w * 16;   // this wave's 16 rows

    // e2 for this split -> LDS once (512 threads x 2 floats)
    e2s[t]       = e2[s * 1024 + t];
    e2s[t + 512] = e2[s * 1024 + 512 + t];

    // ---- persistent z fragments: 16 rows x 256 dims per wave, NAMED scalars ----
    short8v zf0, zf1, zf2, zf3, zf4, zf5, zf6, zf7;
    {
        const float* zr = &z[(size_t)(rw + l15) * DDIM];
#define LOADZ(I, DST)                                                        \
        {                                                                    \
            int d0 = (I) * 32 + quad * 8;                                    \
            float4 f0 = *(const float4*)&zr[d0];                             \
            float4 f1 = *(const float4*)&zr[d0 + 4];                         \
            short8v v;                                                       \
            v[0] = f2bf(f0.x); v[1] = f2bf(f0.y);                            \
            v[2] = f2bf(f0.z); v[3] = f2bf(f0.w);                            \
            v[4] = f2bf(f1.x); v[5] = f2bf(f1.y);                            \
            v[6] = f2bf(f1.z); v[7] = f2bf(f1.w);                            \
            DST = v;                                                         \
        }
        LOADZ(0, zf0) LOADZ(1, zf1) LOADZ(2, zf2) LOADZ(3, zf3)
        LOADZ(4, zf4) LOADZ(5, zf5) LOADZ(6, zf6) LOADZ(7, zf7)
#undef LOADZ
    }

    __syncthreads();   // e2s ready; the ONLY barrier in this kernel

    float v0 = 3.4e38f, v1 = 3.4e38f, v2 = 3.4e38f;
    int   i0 = 0x7fff,  i1 = 0x7fff,  i2 = 0x7fff;

    const char* sbase = ebf_p + (size_t)s * TILES_PER_SPLIT * TILE_BYTES
                      + quad * 512 + l15 * 16;

    // ---- 32 tiles streamed from global/L2, zero synchronization ----
    #pragma unroll 1
    for (int tt = 0; tt < TILES_PER_SPLIT; ++tt) {
        const char* tg = sbase + (size_t)tt * TILE_BYTES;

        float4v acc0 = (float4v)0.0f, acc1 = (float4v)0.0f;

#define STEP(KK, ZF)                                                         \
        {                                                                    \
            short8v a0 = *(const short8v*)(tg + (KK) * 2048);                \
            short8v a1 = *(const short8v*)(tg + (KK) * 2048 + 256);          \
            acc0 = __builtin_amdgcn_mfma_f32_16x16x32_bf16(a0, ZF, acc0, 0, 0, 0); \
            acc1 = __builtin_amdgcn_mfma_f32_16x16x32_bf16(a1, ZF, acc1, 0, 0, 0); \
        }
        STEP(0, zf0) STEP(1, zf1) STEP(2, zf2) STEP(3, zf3)
        STEP(4, zf4) STEP(5, zf5) STEP(6, zf6) STEP(7, zf7)
#undef STEP

        // epilogue: fold tile scores m(k)=e2[k]-2S into per-row top-3
        const int kloc  = tt * TILE_CODES;
        const int kbase = s * 1024 + kloc;
        float4 e2a = *(const float4*)&e2s[kloc + quad * 4];
        float4 e2b = *(const float4*)&e2s[kloc + 16 + quad * 4];
        float m;
        m = fmaf(-2.0f, acc0[0], e2a.x); ins3(m, kbase + quad * 4 + 0,      v0, v1, v2, i0, i1, i2);
        m = fmaf(-2.0f, acc1[0], e2b.x); ins3(m, kbase + 16 + quad * 4 + 0, v0, v1, v2, i0, i1, i2);
        m = fmaf(-2.0f, acc0[1], e2a.y); ins3(m, kbase + quad * 4 + 1,      v0, v1, v2, i0, i1, i2);
        m = fmaf(-2.0f, acc1[1], e2b.y); ins3(m, kbase + 16 + quad * 4 + 1, v0, v1, v2, i0, i1, i2);
        m = fmaf(-2.0f, acc0[2], e2a.z); ins3(m, kbase + quad * 4 + 2,      v0, v1, v2, i0, i1, i2);
        m = fmaf(-2.0f, acc1[2], e2b.z); ins3(m, kbase + 16 + quad * 4 + 2, v0, v1, v2, i0, i1, i2);
        m = fmaf(-2.0f, acc0[3], e2a.w); ins3(m, kbase + quad * 4 + 3,      v0, v1, v2, i0, i1, i2);
        m = fmaf(-2.0f, acc1[3], e2b.w); ins3(m, kbase + 16 + quad * 4 + 3, v0, v1, v2, i0, i1, i2);
    }

    // ---- cross-quad merge via shuffles: 4 quads x top-3 -> split top-3 ----
    {
        float bm0 = 3.4e38f, bm1 = 3.4e38f, bm2 = 3.4e38f;
        int   bk0 = 0x7fff,  bk1 = 0x7fff,  bk2 = 0x7fff;
        #pragma unroll
        for (int q = 0; q < 4; ++q) {
            int src = l15 + q * 16;
            float m0 = __shfl(v0, src); int k0 = __shfl(i0, src);
            float m1 = __shfl(v1, src); int k1 = __shfl(i1, src);
            float m2 = __shfl(v2, src); int k2 = __shfl(i2, src);
            ins3(m0, k0, bm0, bm1, bm2, bk0, bk1, bk2);
            ins3(m1, k1, bm0, bm1, bm2, bk0, bk1, bk2);
            ins3(m2, k2, bm0, bm1, bm2, bk0, bk1, bk2);
        }
        // split-major layout cand[s][n][3]: contiguous per-block writes
        if (quad == 0) {
            size_t base = ((size_t)s * N + (rw + l15)) * 3;
            cand_v[base]     = bm0;  cand_i[base]     = (u16)bk0;
            cand_v[base + 1] = bm1;  cand_i[base + 1] = (u16)bk1;
            cand_v[base + 2] = bm2;  cand_i[base + 2] = (u16)bk2;
        }
    }
}

// ---------------- kernel 4: prefilter + np-faithful re-rank + gather + loss ----------------
// One wave per row. Pool = 6 (2 splits x top-3) sorted by (value,idx); exact
// fp64 dots on 6, numpy-fp32-faithful distance ranking, fused gather+partials.
// (R9 version verbatim -- R13's cross-wave split and R14's ILP tail were both
// within-noise-or-worse; this is the best-measured total.)
__global__ void refine_fused_kernel(const float* __restrict__ z, const float* __restrict__ e,
                                    const float* __restrict__ e2np,
                                    const float* __restrict__ cand_v,
                                    const u16* __restrict__ cand_i,
                                    int* __restrict__ counts, float* __restrict__ partials,
                                    float* __restrict__ out_zq, float* __restrict__ out_idx,
                                    int N) {
    __shared__ float buf[4][DDIM];
    __shared__ float ch[4][16];
    __shared__ float wsum[4];
    const int w = threadIdx.x >> 6;
    const int t = threadIdx.x & 63;
    const int n = blockIdx.x * 4 + w;

    float4 zv = *(const float4*)&z[(size_t)n * DDIM + t * 4];
    *(float4*)&buf[w][t * 4] = zv;
    __syncthreads();
    if (t < 16) ch[w][t] = np_sq_chain(buf[w], t);
    __syncthreads();

    // ---- pool: 6 candidates, (value,idx)-sorted insertion ----
    float bv[6]; int bi[6];
    #pragma unroll
    for (int c = 0; c < 6; ++c) { bv[c] = 3.4e38f; bi[c] = 0x7fffffff; }
    #pragma unroll
    for (int c = 0; c < 6; ++c) {
        int sp = c / 3, j = c - sp * 3;
        size_t off = ((size_t)sp * N + n) * 3 + j;
        float v  = cand_v[off];
        int   id = (int)cand_i[off];
        #pragma unroll
        for (int x = 0; x < 6; ++x) {
            if (v < bv[x] || (v == bv[x] && id < bi[x])) {
                for (int d = 5; d > x; --d) { bv[d] = bv[d - 1]; bi[d] = bi[d - 1]; }
                bv[x] = v; bi[x] = id;
                break;
            }
        }
    }

    float dotf[6];
    #pragma unroll
    for (int c = 0; c < 6; ++c) {
        int k = bi[c];
        float4 ev = *(const float4*)&e[(size_t)k * DDIM + t * 4];
        double p = (double)zv.x * (double)ev.x + (double)zv.y * (double)ev.y
                 + (double)zv.z * (double)ev.z + (double)zv.w * (double)ev.w;
        #pragma unroll
        for (int o = 32; o > 0; o >>= 1) p += __shfl_down(p, o);
        dotf[c] = (float)p;   // correctly-rounded fp32 of exact dot
    }

    int bk = 0;
    if (t == 0) {
        #pragma clang fp contract(off)
        float sx = np_combine16(ch[w]);
        float bd = 3.4e38f;
        bk = 0x7fffffff;
        #pragma unroll
        for (int c = 0; c < 6; ++c) {
            float twod = 2.0f * dotf[c];
            float t1 = sx - twod;
            float d2v = t1 + e2np[bi[c]];
            d2v = fmaxf(d2v, 0.0f);
            float d = sqrtf(d2v);
            if (d < bd || (d == bd && bi[c] < bk)) { bd = d; bk = bi[c]; }
        }
    }
    int wk = __shfl(bk, 0);

    float4 ev = *(const float4*)&e[(size_t)wk * DDIM + t * 4];
    *(float4*)&out_zq[(size_t)n * DDIM + t * 4] = ev;
    float dx = zv.x - ev.x, dy = zv.y - ev.y, dz = zv.z - ev.z, dw = zv.w - ev.w;
    float sq = dx * dx + dy * dy + dz * dz + dw * dw;
    #pragma unroll
    for (int o = 32; o > 0; o >>= 1) sq += __shfl_down(sq, o);
    if (t == 0) {
        wsum[w] = sq;
        atomicAdd(&counts[wk], 1);
        out_idx[n] = (float)wk;
    }
    __syncthreads();
    if (threadIdx.x == 0)
        partials[blockIdx.x] = wsum[0] + wsum[1] + wsum[2] + wsum[3];
}

// ---------------- kernel 5: finalize loss ----------------
__global__ void finalize_kernel(const int* __restrict__ counts, const float* __restrict__ partials,
                                float* __restrict__ out_loss, int K, int NB,
                                float invN, float invND) {
    int t = threadIdx.x;
    double ent = 0.0, sq = 0.0;
    for (int k = t; k < K; k += 256) {
        float p = (float)counts[k] * invN;
        ent += (double)(p * logf(p + 1e-10f));
    }
    for (int i = t; i < NB; i += 256) sq += (double)partials[i];
    #pragma unroll
    for (int o = 32; o > 0; o >>= 1) {
        ent += __shfl_down(ent, o);
        sq  += __shfl_down(sq, o);
    }
    __shared__ double e4[4], s4[4];
    if ((t & 63) == 0) { e4[t >> 6] = ent; s4[t >> 6] = sq; }
    __syncthreads();
    if (t == 0) {
        double esum = e4[0] + e4[1] + e4[2] + e4[3];
        double ssum = s4[0] + s4[1] + s4[2] + s4[3];
        float perp = expf((float)(-esum));
        float mean = (float)ssum * invND;
        out_loss[0] = 1.25f * mean - 0.01f * perp;
    }
}

extern "C" void kernel_launch(void* const* d_in, const int* in_sizes, int n_in,
                              void* d_out, int out_size, void* d_ws, size_t ws_size,
                              hipStream_t stream) {
    const float* z = (const float*)d_in[0];
    const float* e = (const float*)d_in[1];
    const int N = in_sizes[0] / DDIM;   // 32768
    const int K = in_sizes[1] / DDIM;   // 2048

    float* out      = (float*)d_out;
    float* out_zq   = out;
    float* out_loss = out + (size_t)N * DDIM;
    float* out_idx  = out_loss + 1;

    // ws layout (bytes):
    //   counts[K]            @ 0        (8 KB)
    //   e2np[K]              @ 8192     (8 KB)
    //   partials[N/4]        @ 16384    (32 KB)
    //   cand_v[2][N][3] f32  @ 49152    (768 KB)
    //   cand_i[2][N][3] u16  @ 835584   (384 KB)
    //   ebf_p (1 MB panels)  @ 1228800  -> total ~2.2 MB
    int*   counts   = (int*)d_ws;
    float* e2np     = (float*)((char*)d_ws + 8192);
    float* partials = (float*)((char*)d_ws + 16384);
    float* cand_v   = (float*)((char*)d_ws + 49152);
    u16*   cand_i   = (u16*)((char*)d_ws + 835584);
    char*  ebf_p    = (char*)d_ws + 1228800;

    code_norms_np_kernel<<<K, 64, 0, stream>>>(e, e2np, counts);
    convert_permute_e_kernel<<<K * 32 / 256, 256, 0, stream>>>(e, ebf_p);
    vq_cand_kernel<<<dim3(N / ROWS_PER_BLOCK, NSPLIT), 512, 0, stream>>>(z, ebf_p, e2np,
                                                                         cand_v, cand_i, N);
    refine_fused_kernel<<<N / 4, 256, 0, stream>>>(z, e, e2np, cand_v, cand_i,
                                                   counts, partials, out_zq, out_idx, N);
    finalize_kernel<<<1, 256, 0, stream>>>(counts, partials, out_loss, K, N / 4,
                                           1.0f / (float)N, 1.0f / (float)(N * DDIM));
}